// Round 2
// baseline (729.887 us; speedup 1.0000x reference)
//
#include <hip/hip_runtime.h>

#define NEG (-1e30f)

// Problem constants: B=2048, T=256, C=128, L=32, S=65
// ws layout: lp_ext[b][t][j], j=0 blank, j=1..32 labels; stride 33 floats.

// ---------------- Kernel A: log-softmax + gather into ws --------------------
// grid 65536 x 256thr. block -> b = blk/32, t_base = (blk%32)*8 (8 t's/block).
// wave w, half h handles t = t_base + 2w + h; lanes l=0..31 of each half load
// float4 (classes 4l..4l+3).
__global__ __launch_bounds__(256, 8) void ctc_lse_kernel(
    const int* __restrict__ y_true,
    const float* __restrict__ y_pred,
    float* __restrict__ lp_ext)
{
    const int blk    = blockIdx.x;
    const int b      = blk >> 5;
    const int t_base = (blk & 31) << 3;
    const int tid    = threadIdx.x;
    const int wave   = tid >> 6;
    const int lane   = tid & 63;
    const int h      = lane >> 5;
    const int l      = lane & 31;

    __shared__ int lab[32];
    if (tid < 32) lab[tid] = y_true[b * 32 + tid];
    __syncthreads();

    const int t = t_base + wave * 2 + h;
    const float4 v = ((const float4*)(y_pred + ((size_t)b * 256 + t) * 128))[l];

    // sum of exps, no max subtract (logits ~N(0,1), fp32 exp safe)
    float se = __expf(v.x) + __expf(v.y) + __expf(v.z) + __expf(v.w);
    #pragma unroll
    for (int off = 16; off; off >>= 1) se += __shfl_xor(se, off);
    const float lse = __logf(se);

    // gather class c = lab[l] -> slot l+1 (label l). component shuffle.
    const int c   = lab[l];
    const int src = h * 32 + (c >> 2);
    float g0 = __shfl(v.x, src), g1 = __shfl(v.y, src);
    float g2 = __shfl(v.z, src), g3 = __shfl(v.w, src);
    float g  = (c & 2) ? ((c & 1) ? g3 : g2) : ((c & 1) ? g1 : g0);

    float* dst = lp_ext + ((size_t)b * 256 + t) * 33;
    dst[l + 1] = g - lse;
    if (l == 0) dst[0] = v.x - lse;   // blank: class 0 = lane l=0's v.x
}

// ---------------- Kernel B: forward recursion, 1 wave per row --------------
__global__ __launch_bounds__(256, 4) void ctc_alpha_kernel(
    const int* __restrict__ y_true,
    const float* __restrict__ lp_ext,
    float* __restrict__ out)
{
    const int wave = threadIdx.x >> 6;
    const int lane = threadIdx.x & 63;
    const int b    = blockIdx.x * 4 + wave;
    const int s    = lane;                 // state 0..63; state 64 replicated

    const int li    = y_true[b * 32 + (s >> 1)];
    const int lprev = __shfl_up(li, 2);    // lab[(s>>1)-1] for s>=2
    const bool can_skip = (s & 1) && (s >= 3) && (li != lprev);
    const int  lpidx    = (s & 1) ? (1 + (s >> 1)) : 0;

    const float* __restrict__ P = lp_ext + (size_t)b * 256 * 33;

    float alpha = (s == 0) ? P[0] : ((s == 1) ? P[1] : NEG);
    float a64   = NEG;

    #pragma unroll 4
    for (int t = 1; t < 256; ++t) {
        const float* Pt = P + t * 33;
        float lp  = Pt[lpidx];
        float lp0 = Pt[0];

        float a1 = __shfl_up(alpha, 1);
        if (s == 0) a1 = NEG;
        float a2 = __shfl_up(alpha, 2);
        if (!can_skip) a2 = NEG;
        float aold63 = __shfl(alpha, 63);

        float m = fmaxf(fmaxf(alpha, a1), a2);
        alpha = m + __logf(__expf(alpha - m) + __expf(a1 - m) + __expf(a2 - m)) + lp;

        float m2 = fmaxf(a64, aold63);
        a64 = m2 + __logf(__expf(a64 - m2) + __expf(aold63 - m2)) + lp0;
    }

    if (s == 63) {
        float m = fmaxf(alpha, a64);
        out[b] = -(m + __logf(__expf(alpha - m) + __expf(a64 - m)));
    }
}

// ---------------- Fallback: fused single-kernel (R1 version) ---------------
__global__ __launch_bounds__(256, 4) void ctc_loss_fused_kernel(
    const int* __restrict__ y_true,
    const float* __restrict__ y_pred,
    float* __restrict__ out)
{
    const int b    = blockIdx.x;
    const int tid  = threadIdx.x;
    const int lane = tid & 63;
    const int wave = tid >> 6;

    __shared__ int   lab[32];
    __shared__ float lpv[256 * 33];

    if (tid < 32) lab[tid] = y_true[b * 32 + tid];
    __syncthreads();

    const float* __restrict__ Y = y_pred + (size_t)b * 256 * 128;

    for (int t = wave; t < 256; t += 4) {
        float2 v = ((const float2*)(Y + t * 128))[lane];
        float se = __expf(v.x) + __expf(v.y);
        #pragma unroll
        for (int off = 32; off; off >>= 1) se += __shfl_xor(se, off);
        float lse = __logf(se);
        int c = (lane >= 1 && lane <= 32) ? lab[lane - 1] : 0;
        float g0 = __shfl(v.x, c >> 1);
        float g1 = __shfl(v.y, c >> 1);
        float g  = (c & 1) ? g1 : g0;
        if (lane <= 32) lpv[t * 33 + lane] = g - lse;
    }
    __syncthreads();

    if (wave == 0) {
        const int s = lane;
        const bool can_skip = (s & 1) && (s >= 3) && (lab[s >> 1] != lab[(s >> 1) - 1]);
        const int  lpidx    = (s & 1) ? (1 + (s >> 1)) : 0;

        float alpha = (s == 0) ? lpv[0] : ((s == 1) ? lpv[1] : NEG);
        float a64   = NEG;

        for (int t = 1; t < 256; ++t) {
            float a1 = __shfl_up(alpha, 1);
            if (s == 0) a1 = NEG;
            float a2 = __shfl_up(alpha, 2);
            if (!can_skip) a2 = NEG;
            float aold63 = __shfl(alpha, 63);
            float lp0 = lpv[t * 33];
            float lp  = lpv[t * 33 + lpidx];
            float m = fmaxf(fmaxf(alpha, a1), a2);
            alpha = m + __logf(__expf(alpha - m) + __expf(a1 - m) + __expf(a2 - m)) + lp;
            float m2 = fmaxf(a64, aold63);
            a64 = m2 + __logf(__expf(a64 - m2) + __expf(aold63 - m2)) + lp0;
        }

        if (s == 63) {
            float m = fmaxf(alpha, a64);
            out[b] = -(m + __logf(__expf(alpha - m) + __expf(a64 - m)));
        }
    }
}

extern "C" void kernel_launch(void* const* d_in, const int* in_sizes, int n_in,
                              void* d_out, int out_size, void* d_ws, size_t ws_size,
                              hipStream_t stream) {
    const int*   y_true = (const int*)d_in[0];
    const float* y_pred = (const float*)d_in[1];
    float*       out    = (float*)d_out;

    const size_t need = (size_t)2048 * 256 * 33 * sizeof(float);  // 69.2 MB
    if (ws_size >= need) {
        float* lp_ext = (float*)d_ws;
        ctc_lse_kernel<<<2048 * 32, 256, 0, stream>>>(y_true, y_pred, lp_ext);
        ctc_alpha_kernel<<<2048 / 4, 256, 0, stream>>>(y_true, lp_ext, out);
    } else {
        ctc_loss_fused_kernel<<<2048, 256, 0, stream>>>(y_true, y_pred, out);
    }
}

// Round 3
// 574.896 us; speedup vs baseline: 1.2696x; 1.2696x over previous
//
#include <hip/hip_runtime.h>

#define NEG (-1e30f)

// B=2048, T=256, C=128, L=32, S=65. Fused: 512 blocks x 256 thr,
// wave w of block g owns batch row r = g*4+w end-to-end. lp kept in LDS as
// bf16 (err ~O(1) << 23.36 threshold); 70KB LDS -> 2 blocks/CU.

__device__ __forceinline__ float bf16_to_f(unsigned short u) {
    return __uint_as_float(((unsigned int)u) << 16);
}
__device__ __forceinline__ unsigned short f_to_bf16(float x) {
    unsigned int u = __float_as_uint(x);
    u += 0x7FFFu + ((u >> 16) & 1u);      // round-to-nearest-even
    return (unsigned short)(u >> 16);
}
// whole-wave shift-right-by-1 via DPP wave_shr:1 (0x138); lane0 <- NEG fill.
__device__ __forceinline__ float dpp_shr1_neg(float x) {
    return __int_as_float(__builtin_amdgcn_update_dpp(
        __float_as_int(NEG), __float_as_int(x), 0x138, 0xF, 0xF, false));
}

__global__ __launch_bounds__(256, 2) void ctc_fused_kernel(
    const int* __restrict__ y_true,    // [2048,32]
    const float* __restrict__ y_pred,  // [2048,256,128]
    float* __restrict__ out)           // [2048]
{
    __shared__ unsigned short lp[4][256][34]; // [wave][t][j] j=0 blank, 1..32 labels
    __shared__ int labs[4][32];

    const int tid  = threadIdx.x;
    const int wave = tid >> 6;
    const int lane = tid & 63;
    const int r    = blockIdx.x * 4 + wave;

    if (lane < 32) labs[wave][lane] = y_true[r * 32 + lane];
    __syncthreads();

    const float* __restrict__ Y = y_pred + (size_t)r * 256 * 128;

    // ---- Phase 1: per-lane softmax denominator (lane = t), then gather ----
    for (int sl = 0; sl < 4; ++sl) {
        const int t = sl * 64 + lane;
        const float4* __restrict__ row = (const float4*)(Y + (size_t)t * 128);
        float a0 = 0.f, a1 = 0.f, a2 = 0.f, a3 = 0.f;
        float c0 = 0.f;
        #pragma unroll
        for (int k = 0; k < 32; ++k) {
            float4 v = row[k];
            if (k == 0) c0 = v.x;          // class 0 (blank) logit
            a0 += __expf(v.x); a1 += __expf(v.y);
            a2 += __expf(v.z); a3 += __expf(v.w);
        }
        const float lse = __logf((a0 + a1) + (a2 + a3));
        unsigned short* dst = &lp[wave][t][0];
        dst[0] = f_to_bf16(c0 - lse);
        #pragma unroll
        for (int j = 0; j < 32; ++j) {
            const int c = labs[wave][j];   // wave-uniform
            dst[j + 1] = f_to_bf16(Y[(size_t)t * 128 + c] - lse);
        }
    }
    __syncthreads();

    // ---- Phase 2: forward recursion, lane s = state 0..63; a64 in lane 63 ----
    {
        const int s  = lane;
        const int hi = s >> 1;
        const int li = labs[wave][hi];
        const int lm = (hi >= 1) ? labs[wave][hi - 1] : 0;
        const bool can_skip = (s & 1) && (s >= 3) && (li != lm);
        const int  lpidx    = (s & 1) ? (1 + hi) : 0;
        const unsigned short* P = &lp[wave][0][0];

        float alpha = (s == 0) ? bf16_to_f(P[0]) :
                      (s == 1) ? bf16_to_f(P[1]) : NEG;
        float a64 = NEG;   // alpha[64]; only lane 63's copy is meaningful

        #pragma unroll 4
        for (int t = 1; t < 256; ++t) {
            const float lpv = bf16_to_f(P[t * 34 + lpidx]);
            const float lp0 = bf16_to_f(P[t * 34]);

            // alpha[64] = logaddexp(a64, old alpha[63]) + lp(blank); uses OWN old alpha
            float m2   = fmaxf(a64, alpha);
            float a64n = m2 + __logf(__expf(a64 - m2) + __expf(alpha - m2)) + lp0;

            float b1 = dpp_shr1_neg(alpha);    // alpha[s-1], NEG into s=0
            float b2 = dpp_shr1_neg(b1);       // alpha[s-2], NEG into s=0,1
            if (!can_skip) b2 = NEG;
            float m = fmaxf(fmaxf(alpha, b1), b2);
            alpha = m + __logf(__expf(alpha - m) + __expf(b1 - m) + __expf(b2 - m)) + lpv;
            a64 = a64n;
        }

        if (s == 63) {
            float m = fmaxf(alpha, a64);
            out[r] = -(m + __logf(__expf(alpha - m) + __expf(a64 - m)));
        }
    }
}

extern "C" void kernel_launch(void* const* d_in, const int* in_sizes, int n_in,
                              void* d_out, int out_size, void* d_ws, size_t ws_size,
                              hipStream_t stream) {
    const int*   y_true = (const int*)d_in[0];
    const float* y_pred = (const float*)d_in[1];
    float*       out    = (float*)d_out;
    ctc_fused_kernel<<<512, 256, 0, stream>>>(y_true, y_pred, out);
}